// Round 5
// baseline (468.441 us; speedup 1.0000x reference)
//
#include <hip/hip_runtime.h>

// UnarySqrt scan over T=64 steps, N=2^20 channels, values are exact {0,1} floats.
// Bit identities:  out_t = tr | x_t  = tr + x_t*(1-tr)   (disjoint add, exact)
//                  tr'   = x_t & ~tr = x_t*(1-tr)
// so with p = x*(1-tr):  out = tr + p ; tr' = p.
//
// Rounds 1/3 were stuck at 2.4 TB/s regardless of occupancy: VGPR counts
// (32/20) show the compiler kept only ~1 load in flight -> each wave
// serializes on a full memory roundtrip per time step (latency-bound).
// This version forces a depth-8 software pipeline: a rotating 8 x float4
// register buffer, t-loop fully unrolled so buf[t&7] is static register
// indexing. 16 waves/CU x 8 KB in flight = 128 KB/CU, >> Little's-law
// requirement (~10-25 KB) for full HBM bandwidth.

typedef float v4f __attribute__((ext_vector_type(4)));

__global__ __launch_bounds__(256) void UnarySqrt_kernel(
    const v4f* __restrict__ in,      // [T, N/4] as v4f
    const v4f* __restrict__ trace0,  // [N/4] as v4f
    v4f* __restrict__ out,           // [T, N/4] as v4f
    int stride)                       // N/4
{
    int idx = blockIdx.x * blockDim.x + threadIdx.x;
    if (idx >= stride) return;

    v4f tr = trace0[idx];

    // Prime the pipeline: 8 independent loads in flight.
    v4f buf[8];
    #pragma unroll
    for (int j = 0; j < 8; ++j) {
        buf[j] = in[(size_t)j * (size_t)stride + (size_t)idx];
    }

    #pragma unroll
    for (int t = 0; t < 64; ++t) {
        v4f x = buf[t & 7];
        if (t + 8 < 64) {
            buf[t & 7] = in[(size_t)(t + 8) * (size_t)stride + (size_t)idx];
        }
        v4f p = x * (1.0f - tr);
        v4f o = tr + p;
        __builtin_nontemporal_store(o, &out[(size_t)t * (size_t)stride + (size_t)idx]);
        tr = p;
    }
}

extern "C" void kernel_launch(void* const* d_in, const int* in_sizes, int n_in,
                              void* d_out, int out_size, void* d_ws, size_t ws_size,
                              hipStream_t stream) {
    const float* bits   = (const float*)d_in[0];  // [T, N]
    const float* trace0 = (const float*)d_in[1];  // [N]

    int N = in_sizes[1];
    int stride = N / 4;  // N = 1048576 -> divisible by 4

    int block = 256;
    int grid = (stride + block - 1) / block;

    UnarySqrt_kernel<<<grid, block, 0, stream>>>(
        (const v4f*)bits,
        (const v4f*)trace0,
        (v4f*)d_out,
        stride);
}